// Round 1
// baseline (126.670 us; speedup 1.0000x reference)
//
#include <hip/hip_runtime.h>

// out_real[j,c,s] = cos(a_j) * x[j,c,s];  out_imag[j,c,s] = sin(a_j) * x[j,c,s]
// a_j = -2*pi*freq * j / FS.  Memory-bound: 604 MB traffic/call, floor ~96 us.

constexpr int   N_WIN = 512;
constexpr int   ROW   = 3 * 32768;   // elements sharing one angle (per j)
constexpr int   ROW4  = ROW / 4;     // float4 per row = 24576
constexpr float FS_HZ = 30.0f;
constexpr float TWO_PI = 6.28318530717958647692f;

__global__ __launch_bounds__(256) void
modulate_kernel(const float* __restrict__ x,
                const float* __restrict__ freq,
                float* __restrict__ out_r,
                float* __restrict__ out_i,
                int bpr /* blocks per row */) {
    const int j = blockIdx.x / bpr;          // window-sample index 0..511
    const int b = blockIdx.x % bpr;          // block within the row

    // One accurate sincos per thread, amortized over ~ROW4/(bpr*256) = 24 float4 iters.
    const float a = -TWO_PI * freq[0] * (float)j / FS_HZ;
    float s, c;
    sincosf(a, &s, &c);

    const float4* __restrict__ xv = reinterpret_cast<const float4*>(x)     + (size_t)j * ROW4;
    float4*       __restrict__ rv = reinterpret_cast<float4*>(out_r)       + (size_t)j * ROW4;
    float4*       __restrict__ iv = reinterpret_cast<float4*>(out_i)       + (size_t)j * ROW4;

    const int stride = bpr * (int)blockDim.x;
    for (int i = b * (int)blockDim.x + (int)threadIdx.x; i < ROW4; i += stride) {
        const float4 v = xv[i];
        float4 r, im;
        r.x  = c * v.x;  r.y  = c * v.y;  r.z  = c * v.z;  r.w  = c * v.w;
        im.x = s * v.x;  im.y = s * v.y;  im.z = s * v.z;  im.w = s * v.w;
        rv[i] = r;
        iv[i] = im;
    }
}

extern "C" void kernel_launch(void* const* d_in, const int* in_sizes, int n_in,
                              void* d_out, int out_size, void* d_ws, size_t ws_size,
                              hipStream_t stream) {
    const float* x    = (const float*)d_in[0];   // (512, 3, 32768) fp32
    const float* freq = (const float*)d_in[1];   // (1,) fp32

    float* out_r = (float*)d_out;                          // ax_real, 50331648 floats
    float* out_i = out_r + (size_t)N_WIN * ROW;            // ax_imag follows flat

    const int bpr = 4;                                     // 4 blocks x 512 rows = 2048 blocks
    dim3 grid(N_WIN * bpr), block(256);
    modulate_kernel<<<grid, block, 0, stream>>>(x, freq, out_r, out_i, bpr);
}

// Round 3
// 92.046 us; speedup vs baseline: 1.3762x; 1.3762x over previous
//
#include <hip/hip_runtime.h>

// out_real[j,c,s] = cos(a_j) * x[j,c,s];  out_imag[j,c,s] = sin(a_j) * x[j,c,s]
// a_j = -2*pi*freq * j / FS.
// Memory-bound: 201 MB read + 402 MB write per call. Floor ~96 us @ 6.3 TB/s.
// R2: nontemporal stores via clang native vector type (HIP float4 is a class
//     and the builtin rejects it) + x2 unroll for load MLP.

typedef float f32x4 __attribute__((ext_vector_type(4)));

constexpr int   N_WIN = 512;
constexpr int   ROW   = 3 * 32768;   // elements sharing one angle (per j)
constexpr int   ROW4  = ROW / 4;     // float4 per row = 24576
constexpr int   BPR   = 4;           // blocks per row
constexpr int   TPB   = 256;
constexpr int   STRIDE = BPR * TPB;          // 1024 threads per row
constexpr int   ITERS  = ROW4 / STRIDE;      // 24 float4 per thread
constexpr float FS_HZ  = 30.0f;
constexpr float TWO_PI = 6.28318530717958647692f;

__global__ __launch_bounds__(TPB) void
modulate_kernel(const float* __restrict__ x,
                const float* __restrict__ freq,
                float* __restrict__ out_r,
                float* __restrict__ out_i) {
    const int j = blockIdx.x / BPR;          // window-sample index 0..511
    const int b = blockIdx.x % BPR;          // block within the row

    // One accurate sincos per thread, amortized over 24 float4 iterations.
    const float a = -TWO_PI * freq[0] * (float)j / FS_HZ;
    float s, c;
    sincosf(a, &s, &c);

    const f32x4* __restrict__ xv = reinterpret_cast<const f32x4*>(x)   + (size_t)j * ROW4;
    f32x4*       __restrict__ rv = reinterpret_cast<f32x4*>(out_r)     + (size_t)j * ROW4;
    f32x4*       __restrict__ iv = reinterpret_cast<f32x4*>(out_i)     + (size_t)j * ROW4;

    int i = b * TPB + (int)threadIdx.x;
    #pragma unroll
    for (int it = 0; it < ITERS / 2; ++it) {
        // issue both loads before any dependent store (MLP)
        const f32x4 v0 = xv[i];
        const f32x4 v1 = xv[i + STRIDE];

        const f32x4 r0 = c * v0;
        const f32x4 i0 = s * v0;
        const f32x4 r1 = c * v1;
        const f32x4 i1 = s * v1;

        __builtin_nontemporal_store(r0, &rv[i]);
        __builtin_nontemporal_store(i0, &iv[i]);
        __builtin_nontemporal_store(r1, &rv[i + STRIDE]);
        __builtin_nontemporal_store(i1, &iv[i + STRIDE]);

        i += 2 * STRIDE;
    }
}

extern "C" void kernel_launch(void* const* d_in, const int* in_sizes, int n_in,
                              void* d_out, int out_size, void* d_ws, size_t ws_size,
                              hipStream_t stream) {
    const float* x    = (const float*)d_in[0];   // (512, 3, 32768) fp32
    const float* freq = (const float*)d_in[1];   // (1,) fp32

    float* out_r = (float*)d_out;                      // ax_real, 50331648 floats
    float* out_i = out_r + (size_t)N_WIN * ROW;        // ax_imag follows flat

    dim3 grid(N_WIN * BPR), block(TPB);
    modulate_kernel<<<grid, block, 0, stream>>>(x, freq, out_r, out_i);
}